// Round 5
// baseline (229.223 us; speedup 1.0000x reference)
//
#include <hip/hip_runtime.h>

// LIF scan: z [B=32, T=1024, H=512] fp32 -> out [32,1024,512] fp32
//   V_t = 0.9*V_{t-1} + z[:,t-1,:] - (V_{t-1} > 1)      (exact fp32 op order)
//   out[:,t,:] = (V_t > 1) ? 1 : 0,  out[:,0,:] = 0
//
// R7 lesson: compact writes via ws + transpose pass: scan improved only
//   modestly, extra pass cost more than it saved. BOTH streams need full-row
//   granularity, in ONE pass.
// R8: segmented ripple. Grid = 8 segments x 32 batches = 256 blocks
//   (1024 thr, 128 KB LDS -> exactly 1 block/CU, all co-resident).
//   Block (b,seg) owns t-rows [seg*128, seg*128+128) of batch b:
//     z read  = 256 KB contiguous (8 producer waves, GLDS dwordx4)
//     spikes  = full 2 KB rows (8 consumer waves x 256 B, one CU, one phase)
//   V state (512 fp32) handed off via ws with agent-scope release/acquire
//   flags; segment chains ripple (~6 us serial floor) while all blocks'
//   memory streams in parallel. Flags memset per launch (ws is re-poisoned).
//   bid = seg*32 + b: seg-0 blocks dispatch first; batch stays on one XCD.

#define LIF_H 512
#define LIF_T 1024
#define NSEG 8
#define SEGT 128                    // t-steps per segment
#define SUBT 32                     // rows per sub-chunk (64 KB)
#define NSUB 4
#define NCONS 8
#define NPROD 8
#define NTHREADS ((NCONS + NPROD) * 64)      // 1024
#define BUF_FLOATS (SUBT * LIF_H)            // 16384 floats = 64 KB
#define VBUF_FLOATS (32 * NSEG * LIF_H)      // 131072 floats = 512 KB
#define VBUF_BYTES (VBUF_FLOATS * sizeof(float))
#define FLAG_BYTES (32 * NSEG * sizeof(int))
#define WS_NEED (VBUF_BYTES + FLAG_BYTES)

#define GLDS(gptr, lptr)                                                     \
    __builtin_amdgcn_global_load_lds(                                        \
        (const __attribute__((address_space(1))) void*)(gptr),               \
        (__attribute__((address_space(3))) void*)(lptr), 16, 0, 0)

// ---------------- R8 main kernel: segmented ripple ----------------
__global__ __launch_bounds__(NTHREADS, 1) void lif_seg(const float* __restrict__ z,
                                                       float* __restrict__ out,
                                                       float* __restrict__ vbuf,
                                                       int* __restrict__ flags) {
    extern __shared__ float lds[];          // 2 x 64 KB

    const int tid  = threadIdx.x;
    const int wave = tid >> 6;
    const int lane = tid & 63;
    const int bid  = blockIdx.x;            // 0..255
    const int b    = bid & 31;
    const int seg  = bid >> 5;

    const float* zs = z + (size_t)b * (LIF_T * LIF_H) + (size_t)seg * SEGT * LIF_H;
    float*       ob = out + (size_t)b * (LIF_T * LIF_H);
    const int col = (wave & 7) * 64 + lane; // consumer column 0..511

    float V = 0.0f;
    float r = 0.0f;

    if (wave >= NCONS) {
        // ---- producers: stage sub0 -> buf0, sub1 -> buf1 ----
        const int p = wave - NCONS;         // 0..7
#pragma unroll
        for (int j = 0; j < 8; ++j)
            GLDS(zs + (p * 8 + j) * 256 + lane * 4, &lds[(p * 8 + j) * 256]);
#pragma unroll
        for (int j = 0; j < 8; ++j)
            GLDS(zs + SUBT * LIF_H + (p * 8 + j) * 256 + lane * 4,
                 &lds[BUF_FLOATS + (p * 8 + j) * 256]);
        __builtin_amdgcn_sched_barrier(0);
        asm volatile("s_waitcnt vmcnt(8)" ::: "memory");   // sub0 landed
    } else {
        // ---- consumers: get incoming V ----
        if (seg == 0) {
            ob[col] = 0.0f;                 // t = 0 row
        } else {
            const int fi = (seg - 1) * 32 + b;
            while (__hip_atomic_load(&flags[fi], __ATOMIC_RELAXED,
                                     __HIP_MEMORY_SCOPE_AGENT) < NCONS)
                __builtin_amdgcn_s_sleep(2);
            __builtin_amdgcn_fence(__ATOMIC_ACQUIRE, "agent");
            V = vbuf[(size_t)fi * LIF_H + col];
            r = (V > 1.0f) ? 1.0f : 0.0f;   // reset = spike of prev step
        }
    }
    __builtin_amdgcn_s_barrier();

#define CHAIN(N)                                                             \
    _Pragma("unroll")                                                        \
    for (int i = 0; i < (N); ++i) {                                          \
        const float u  = __fadd_rn(__fmul_rn(0.9f, V), rb[i]);               \
        const float Vn = __fsub_rn(u, r);                                    \
        const float sp = (Vn > 1.0f) ? 1.0f : 0.0f;                          \
        ob[(size_t)(s0 + i + 1) * LIF_H + col] = sp;                         \
        r = sp;                                                              \
        V = Vn;                                                              \
    }

#pragma unroll 1
    for (int c = 0; c < NSUB; ++c) {
        float rb[SUBT];
        if (wave < NCONS) {
            // copy my column of buf(c&1) to regs; MUST drain before barrier A
            // (producers overwrite this same buffer right after barrier A)
            const float* lb = &lds[(c & 1) * BUF_FLOATS];
#pragma unroll
            for (int i = 0; i < SUBT; ++i) rb[i] = lb[i * LIF_H + col];
            asm volatile("s_waitcnt lgkmcnt(0)" ::: "memory");
            __builtin_amdgcn_sched_barrier(0);
        }
        __builtin_amdgcn_s_barrier();       // A

        if (wave < NCONS) {
            const int s0 = seg * SEGT + c * SUBT;
            if (seg == NSEG - 1 && c == NSUB - 1) {
                CHAIN(SUBT - 1);            // steps 993..1023
            } else {
                CHAIN(SUBT);
            }
        } else {
            const int p = wave - NCONS;
            if (c + 2 < NSUB) {
                // stage sub c+2 into buf(c&1); drain sub c+1 (8 newest in flight)
                const float* src = zs + (size_t)(c + 2) * SUBT * LIF_H;
                float* dst = &lds[(c & 1) * BUF_FLOATS];
#pragma unroll
                for (int j = 0; j < 8; ++j)
                    GLDS(src + (p * 8 + j) * 256 + lane * 4,
                         &dst[(p * 8 + j) * 256]);
                __builtin_amdgcn_sched_barrier(0);
                asm volatile("s_waitcnt vmcnt(8)" ::: "memory");
            } else if (c + 2 == NSUB) {
                asm volatile("s_waitcnt vmcnt(0)" ::: "memory");  // sub3 landed
            }
        }
        __builtin_amdgcn_s_barrier();       // B
    }

    // ---- publish V state for the next segment ----
    if (wave < NCONS && seg < NSEG - 1) {
        const int fi = seg * 32 + b;
        vbuf[(size_t)fi * LIF_H + col] = V;
        asm volatile("s_waitcnt vmcnt(0)" ::: "memory");
        if (lane == 0)
            __hip_atomic_fetch_add(&flags[fi], 1, __ATOMIC_RELEASE,
                                   __HIP_MEMORY_SCOPE_AGENT);
    }
#undef CHAIN
}

// ---------------- fallback: R4 direct kernel (ws too small) ----------------
#define CH 128
#define FNPROD 4
#define FNTHREADS (64 * (1 + FNPROD))

__global__ __launch_bounds__(FNTHREADS, 1) void lif_direct(const float* __restrict__ z,
                                                           float* __restrict__ out) {
    __shared__ float slds[2][CH * 64];

    const int tid  = threadIdx.x;
    const int wave = tid >> 6;
    const int lane = tid & 63;
    const int bid  = blockIdx.x;
    const int b    = bid >> 3;
    const int h0   = (bid & 7) << 6;

    const float* zb = z   + b * (LIF_T * LIF_H) + h0;
    float*       ob = out + b * (LIF_T * LIF_H) + h0;

    if (wave == 0) {
        ob[lane] = 0.0f;
    } else {
        const int p = wave - 1;
#pragma unroll
        for (int j = 0; j < 8; ++j) {
            const int r0 = p * 32 + j * 4;
            GLDS(zb + (r0 + (lane >> 4)) * LIF_H + (lane & 15) * 4,
                 &slds[0][r0 * 64]);
        }
        __builtin_amdgcn_sched_barrier(0);
        asm volatile("s_waitcnt vmcnt(0)" ::: "memory");
    }
    __builtin_amdgcn_s_barrier();

    float V = 0.0f, r = 0.0f;

#define LDRB(rb, sub)                                                        \
    _Pragma("unroll")                                                        \
    for (int i = 0; i < 32; ++i) rb[i] = lb[((sub) * 32 + i) * 64 + lane];

#define CHAIND(rb, s0, N)                                                    \
    _Pragma("unroll")                                                        \
    for (int i = 0; i < (N); ++i) {                                          \
        const float u  = __fadd_rn(__fmul_rn(0.9f, V), rb[i]);               \
        const float Vn = __fsub_rn(u, r);                                    \
        const float sp = (Vn > 1.0f) ? 1.0f : 0.0f;                          \
        ob[((s0) + i + 1) * LIF_H + lane] = sp;                              \
        r = sp;                                                              \
        V = Vn;                                                              \
    }

#pragma unroll 1
    for (int c = 0; c < 8; ++c) {
        if (wave > 0) {
            if (c + 1 < 8) {
                const int p = wave - 1;
                float* dst = slds[(c + 1) & 1];
                const float* src = zb + (c + 1) * CH * LIF_H;
#pragma unroll
                for (int j = 0; j < 8; ++j) {
                    const int r0 = p * 32 + j * 4;
                    GLDS(src + (r0 + (lane >> 4)) * LIF_H + (lane & 15) * 4,
                         &dst[r0 * 64]);
                }
                __builtin_amdgcn_sched_barrier(0);
                asm volatile("s_waitcnt vmcnt(0)" ::: "memory");
            }
        } else {
            const float* lb = slds[c & 1];
            const int s0 = c * CH;
            float rbA[32], rbB[32];
            LDRB(rbA, 0);
            LDRB(rbB, 1);
            __builtin_amdgcn_sched_barrier(0);
            CHAIND(rbA, s0 + 0, 32);
            LDRB(rbA, 2);
            __builtin_amdgcn_sched_barrier(0);
            CHAIND(rbB, s0 + 32, 32);
            LDRB(rbB, 3);
            __builtin_amdgcn_sched_barrier(0);
            CHAIND(rbA, s0 + 64, 32);
            __builtin_amdgcn_sched_barrier(0);
            if (c < 7) {
                CHAIND(rbB, s0 + 96, 32);
            } else {
                CHAIND(rbB, s0 + 96, 31);
            }
        }
        __builtin_amdgcn_s_barrier();
    }
}

extern "C" void kernel_launch(void* const* d_in, const int* in_sizes, int n_in,
                              void* d_out, int out_size, void* d_ws, size_t ws_size,
                              hipStream_t stream) {
    const float* z = (const float*)d_in[0];
    float* out = (float*)d_out;
    if (ws_size >= WS_NEED) {
        float* vbuf = (float*)d_ws;
        int* flags = (int*)((char*)d_ws + VBUF_BYTES);
        hipMemsetAsync(flags, 0, FLAG_BYTES, stream);   // ws is re-poisoned
        hipLaunchKernelGGL(lif_seg, dim3(256), dim3(NTHREADS),
                           2 * BUF_FLOATS * sizeof(float), stream,
                           z, out, vbuf, flags);
    } else {
        hipLaunchKernelGGL(lif_direct, dim3(256), dim3(FNTHREADS), 0, stream, z, out);
    }
}

// Round 7
// 116.193 us; speedup vs baseline: 1.9728x; 1.9728x over previous
//
#include <hip/hip_runtime.h>

// LIF scan: z [B=32, T=1024, H=512] fp32 -> out [32,1024,512] fp32
//   V_t = 0.9*V_{t-1} + z[:,t-1,:] - (V_{t-1} > 1)      (exact fp32 op order)
//   out[:,t,:] = (V_t > 1) ? 1 : 0,  out[:,0,:] = 0
//
// Evidence ladder:
//   R4 (this structure, bid=b*8+s): 42.7 us, 2.36 TB/s.
//   R5 triple-buffer/counted-vmcnt: 48.9 -> exposed latency NOT the issue.
//   R6 64 fat blocks: 1.75 TB/s = 64 x 27 GB/s per-CU streaming cap.
//   R8 ripple: 0.64 TB/s = ~32 active CUs x cap. Streams must stay on 256 CUs.
//   R9 bench attempt: container infra failure (no data) -> resubmitting.
// R9 theory: R4's loss is DRAM/L2 row locality. With bid=b*8+s the 8
//   sibling blocks covering one batch's 2 KB rows land on 8 DIFFERENT XCDs
//   (XCD = bid%8 = s): every L2 fetches/writes back disjoint 2-line islands
//   of each row. Fix: decode bid = s*32 + b so XCD = bid%8 = b%8 -> all 8
//   siblings of a batch share one XCD. Each XCD's L2 then misses/evicts
//   COMPLETE rows (16 consecutive lines, phase-aligned requestors) for both
//   the z-read and the spike-write-back streams. Only the bid decode
//   changes vs R4 (clean A/B vs its measured 42.7 us).

#define LIF_H 512
#define LIF_T 1024
#define CH 128            // timesteps per superchunk (32 KB per buffer)
#define NCH 8
#define NPROD 4
#define NTHREADS (64 * (1 + NPROD))

#define GLDS(gptr, lptr)                                                     \
    __builtin_amdgcn_global_load_lds(                                        \
        (const __attribute__((address_space(1))) void*)(gptr),               \
        (__attribute__((address_space(3))) void*)(lptr), 16, 0, 0)

__global__ __launch_bounds__(NTHREADS, 1) void lif_kernel(const float* __restrict__ z,
                                                          float* __restrict__ out) {
    __shared__ float lds[2][CH * 64];

    const int tid  = threadIdx.x;
    const int wave = tid >> 6;
    const int lane = tid & 63;
    const int bid  = blockIdx.x;        // 0..255
    // R9: bid = s*32 + b (was b*8+s). XCD = bid%8 = b%8 -> siblings colocate.
    const int b    = bid & 31;          // batch
    const int h0   = (bid >> 5) << 6;   // 64-wide h-slice index s = bid>>5

    const float* zb = z   + b * (LIF_T * LIF_H) + h0;   // row t = zb + t*512
    float*       ob = out + b * (LIF_T * LIF_H) + h0;

    // ---- prologue: stage chunk 0; consumer zeroes the t=0 row ----
    if (wave == 0) {
        ob[lane] = 0.0f;
    } else {
        const int p = wave - 1;         // 0..3
#pragma unroll
        for (int j = 0; j < 8; ++j) {
            const int r0 = p * 32 + j * 4;
            GLDS(zb + (r0 + (lane >> 4)) * LIF_H + (lane & 15) * 4,
                 &lds[0][r0 * 64]);
        }
        __builtin_amdgcn_sched_barrier(0);
        asm volatile("s_waitcnt vmcnt(0)" ::: "memory");
    }
    __builtin_amdgcn_s_barrier();

    float V = 0.0f;
    float r = 0.0f;                     // reset = previous spike (V0=0 -> 0)

#define LDRB(rb, sub)                                                        \
    _Pragma("unroll")                                                        \
    for (int i = 0; i < 32; ++i) rb[i] = lb[((sub) * 32 + i) * 64 + lane];

#define CHAIN(rb, s0, N)                                                     \
    _Pragma("unroll")                                                        \
    for (int i = 0; i < (N); ++i) {                                          \
        const float u  = __fadd_rn(__fmul_rn(0.9f, V), rb[i]);               \
        const float Vn = __fsub_rn(u, r);                                    \
        const float sp = (Vn > 1.0f) ? 1.0f : 0.0f;                          \
        ob[((s0) + i + 1) * LIF_H + lane] = sp;                              \
        r = sp;                                                              \
        V = Vn;                                                              \
    }

#pragma unroll 1
    for (int c = 0; c < NCH; ++c) {
        if (wave > 0) {
            // ---- producers: stage chunk c+1 into the other buffer ----
            if (c + 1 < NCH) {
                const int p = wave - 1;
                float* dst = lds[(c + 1) & 1];
                const float* src = zb + (c + 1) * CH * LIF_H;
#pragma unroll
                for (int j = 0; j < 8; ++j) {
                    const int r0 = p * 32 + j * 4;
                    GLDS(src + (r0 + (lane >> 4)) * LIF_H + (lane & 15) * 4,
                         &dst[r0 * 64]);
                }
                __builtin_amdgcn_sched_barrier(0);
                asm volatile("s_waitcnt vmcnt(0)" ::: "memory");
            }
        } else {
            // ---- consumer: scan chunk c from LDS (reg double-buffered) ----
            const float* lb = lds[c & 1];
            const int s0 = c * CH;
            float rbA[32], rbB[32];
            LDRB(rbA, 0);
            LDRB(rbB, 1);
            __builtin_amdgcn_sched_barrier(0);
            CHAIN(rbA, s0 + 0, 32);
            LDRB(rbA, 2);
            __builtin_amdgcn_sched_barrier(0);
            CHAIN(rbB, s0 + 32, 32);
            LDRB(rbB, 3);
            __builtin_amdgcn_sched_barrier(0);
            CHAIN(rbA, s0 + 64, 32);
            __builtin_amdgcn_sched_barrier(0);
            if (c < NCH - 1) {
                CHAIN(rbB, s0 + 96, 32);
            } else {
                CHAIN(rbB, s0 + 96, 31);   // steps 992..1022
            }
        }
        __builtin_amdgcn_s_barrier();
    }
}

extern "C" void kernel_launch(void* const* d_in, const int* in_sizes, int n_in,
                              void* d_out, int out_size, void* d_ws, size_t ws_size,
                              hipStream_t stream) {
    const float* z = (const float*)d_in[0];
    float* out = (float*)d_out;
    hipLaunchKernelGGL(lif_kernel, dim3(256), dim3(NTHREADS), 0, stream, z, out);
}